// Round 4
// baseline (521.013 us; speedup 1.0000x reference)
//
#include <hip/hip_runtime.h>
#include <stdint.h>

// HopAttentionLayer: B=256, T=64, N=2048, D=128, fp32.
// attention[b,n] = softmax_n( T * dot(context[b,n,:], W[D:2D]) )
//   (tgt_term[b] and T*b0 are constant over n -> cancel in softmax)
// out[b,n,d] = attention[b,n] * context[b,n,d]
//
// R6: fused, but at 32 waves/CU (the empirical discriminator for HBM BW:
// every >=4.5 TB/s config had 32 waves/CU; every 16-wave fused variant sat
// at 2.4-3.0 TB/s regardless of barriers (R4) or per-wave ILP (R5)).
//  - grid 1024 x 512 thr = 4 blocks/CU x 8 waves = 32 waves/CU
//  - QPB=4 quarters/batch, partial softmax per block, merged via
//    device-scope atomics (R4 mechanism, proven correct)
//  - __launch_bounds__(512,8) caps VGPR at 64 -> guaranteed co-residency;
//    sibling blocks have contiguous IDs -> dispatch-order progress
//  - phase-3 re-read is block-local 256 KiB (L3-hot); nt stores keep the
//    output stream from evicting ctx lines.

#define B_DIM 256
#define N_DIM 2048
#define D_DIM 128
#define DVEC  (D_DIM / 4)        // 32 float4 per row
#define T_SCALE 64.0f
#define QPB   4                  // blocks (quarters) per batch
#define ROWS  (N_DIM / QPB)      // 512 rows per block
#define NTHR  512                // 8 waves

typedef float f4v __attribute__((ext_vector_type(4)));

union ms_pack { struct { float m, s; } f; unsigned long long u; };

__global__ __launch_bounds__(NTHR, 8)
void k_hop(const float* __restrict__ ctx, const float* __restrict__ W,
           float* __restrict__ out,
           unsigned long long* __restrict__ ws_ms,   // [B][QPB] packed (m,s)
           unsigned int* __restrict__ ws_flag) {     // [B] arrival counters
    const int tid  = threadIdx.x;
    const int wave = tid >> 6;          // 0..7
    const int lane = tid & 63;
    const int sub  = lane & 31;         // lane within half-wave
    const int half = lane >> 5;
    const int g    = blockIdx.x >> 2;   // batch
    const int q    = blockIdx.x & 3;    // quarter

    __shared__ float sc[ROWS];          // scores -> probabilities (2 KiB)
    __shared__ float redm[8];
    __shared__ float reds[8];
    __shared__ float s_rs;

    const size_t rbase = (size_t)g * N_DIM + (size_t)q * ROWS;
    const f4v* __restrict__ c4 = (const f4v*)ctx + rbase * DVEC;
    f4v*       __restrict__ o4 = (f4v*)out + rbase * DVEC;

    const f4v wc = ((const f4v*)(W + D_DIM))[sub];   // Wc fragment per lane

    // ---- Phase 1: sc[n] = T * dot(ctx[row,:], Wc) ----
    // 8 waves x 2 rows/iter = 16 rows (8 KiB) per block-iteration.
    #pragma unroll 4
    for (int it = 0; it < ROWS / 16; ++it) {         // 32 iterations
        const int n = it * 16 + wave * 2 + half;
        const f4v v = c4[(size_t)n * DVEC + sub];
        float p = v.x * wc.x + v.y * wc.y + v.z * wc.z + v.w * wc.w;
        #pragma unroll
        for (int m = 1; m < 32; m <<= 1) p += __shfl_xor(p, m, 64); // in-half
        if (sub == 0) sc[n] = T_SCALE * p;
    }
    __syncthreads();

    // ---- Phase 2a: block-partial max & sum-of-exp (1 score/thread) ----
    const float v0 = sc[tid];
    float mx = v0;
    #pragma unroll
    for (int m = 1; m < 64; m <<= 1) mx = fmaxf(mx, __shfl_xor(mx, m, 64));
    if (lane == 0) redm[wave] = mx;
    __syncthreads();
    float mq = redm[0];
    #pragma unroll
    for (int i = 1; i < 8; ++i) mq = fmaxf(mq, redm[i]);

    const float e0 = __expf(v0 - mq);
    float sm = e0;
    #pragma unroll
    for (int m = 1; m < 64; m <<= 1) sm += __shfl_xor(sm, m, 64);
    if (lane == 0) reds[wave] = sm;
    sc[tid] = e0;                       // own element only: no hazard
    __syncthreads();
    float sq = reds[0];
    #pragma unroll
    for (int i = 1; i < 8; ++i) sq += reds[i];

    // ---- Phase 2b: merge the 4 sibling partials (device-scope atomics) ----
    if (tid == 0) {
        ms_pack pk; pk.f.m = mq; pk.f.s = sq;
        __hip_atomic_store(&ws_ms[g * QPB + q], pk.u,
                           __ATOMIC_RELAXED, __HIP_MEMORY_SCOPE_AGENT);
        __hip_atomic_fetch_add(&ws_flag[g], 1u,
                               __ATOMIC_RELEASE, __HIP_MEMORY_SCOPE_AGENT);
        while (__hip_atomic_load(&ws_flag[g], __ATOMIC_ACQUIRE,
                                 __HIP_MEMORY_SCOPE_AGENT) < QPB)
            __builtin_amdgcn_s_sleep(2);
        ms_pack pp[QPB];
        float M = -3.4e38f;
        #pragma unroll
        for (int i = 0; i < QPB; ++i) {
            pp[i].u = __hip_atomic_load(&ws_ms[g * QPB + i],
                                        __ATOMIC_RELAXED,
                                        __HIP_MEMORY_SCOPE_AGENT);
            M = fmaxf(M, pp[i].f.m);
        }
        float S = 0.f;
        #pragma unroll
        for (int i = 0; i < QPB; ++i) S += pp[i].f.s * __expf(pp[i].f.m - M);
        s_rs = __expf(mq - M) / S;      // rescale for THIS block's e-values
    }
    __syncthreads();
    sc[tid] *= s_rs;
    __syncthreads();

    // ---- Phase 3: out[row,:] = sc[row] * ctx[row,:] (re-read L3-hot) ----
    #pragma unroll 8
    for (int i = 0; i < (ROWS * DVEC) / NTHR; ++i) {  // 32 iterations
        const int f = i * NTHR + tid;
        const float w = sc[f >> 5];
        f4v v = c4[f];
        v *= w;
        __builtin_nontemporal_store(v, &o4[f]);
    }
}

extern "C" void kernel_launch(void* const* d_in, const int* in_sizes, int n_in,
                              void* d_out, int out_size, void* d_ws, size_t ws_size,
                              hipStream_t stream) {
    (void)in_sizes; (void)n_in; (void)out_size; (void)ws_size;
    // d_in[0] = targetsentence_emb (unused: cancels in softmax)
    // d_in[1] = context_emb, d_in[2] = W, d_in[3] = b (unused: cancels)
    const float* ctx = (const float*)d_in[1];
    const float* W   = (const float*)d_in[2];
    float* out       = (float*)d_out;

    unsigned long long* ws_ms = (unsigned long long*)d_ws;           // 8 KiB
    unsigned int* ws_flag     = (unsigned int*)((char*)d_ws + 8192); // 1 KiB

    hipMemsetAsync(ws_flag, 0, B_DIM * sizeof(unsigned int), stream);
    hipLaunchKernelGGL(k_hop, dim3(B_DIM * QPB), dim3(NTHR), 0, stream,
                       ctx, W, out, ws_ms, ws_flag);
}

// Round 5
// 488.979 us; speedup vs baseline: 1.0655x; 1.0655x over previous
//
#include <hip/hip_runtime.h>

// HopAttentionLayer: B=256, T=64, N=2048, D=128, fp32.
// attention[b,n] = softmax_n( T * dot(context[b,n,:], W[D:2D]) )
//   (tgt_term[b] and T*b0 are constant over n -> cancel in softmax)
// out[b,n,d] = attention[b,n] * context[b,n,d]
//
// R7: R3 fused structure, with ALL nontemporal hints removed.
// A/B isolates the store path: fillBuffer (plain stores) = 6.5 TB/s and
// m13 float4 copy = 6.3 TB/s, while every nt-store variant of ours sits
// at 2.4-3.0 TB/s regardless of occupancy (R6: 78% occ, still 2.4),
// barriers (R4), or per-wave ILP (R5). Hypothesis: nt no-allocate stores
// drain through a narrow write-combine path (~2 TB/s); normal stores
// absorb into L2 and evict lazily at full HBM rate.
// The nt hint's original purpose (protect cached ctx) is moot here: the
// phase-3 re-read is block-local (1 MiB) and immediate -> L2/MALL-hit,
// as FETCH_SIZE=252 MB (cold read only) already proves.

#define B_DIM 256
#define N_DIM 2048
#define D_DIM 128
#define DVEC  (D_DIM / 4)      // 32 float4 per row
#define NTHR  1024             // 16 waves
#define T_SCALE 64.0f

typedef float f4v __attribute__((ext_vector_type(4)));

__global__ __launch_bounds__(NTHR)
void k_fused(const float* __restrict__ ctx, const float* __restrict__ W,
             float* __restrict__ out) {
    const int tid  = threadIdx.x;
    const int wave = tid >> 6;          // 0..15
    const int lane = tid & 63;
    const int sub  = lane & 31;         // lane within half-wave
    const int half = lane >> 5;
    const int b    = blockIdx.x;

    __shared__ float sm[N_DIM];         // scores -> probabilities (8 KiB)
    __shared__ float red[16];

    const size_t cbase = (size_t)b * ((size_t)N_DIM * DVEC);
    const f4v* __restrict__ c4 = (const f4v*)ctx + cbase;
    f4v*       __restrict__ o4 = (f4v*)out + cbase;

    const f4v wc = ((const f4v*)(W + D_DIM))[sub];   // Wc fragment, per lane

    // ---- Phase 1: sm[n] = T * dot(ctx[b,n,:], Wc) ----
    // half-wave (32 lanes) per row: one float4/lane, 5-step shfl reduce.
    // wave reads rows {it*32 + wave*2, +1} = 1 KiB contiguous.
    #pragma unroll 4
    for (int it = 0; it < N_DIM / 32; ++it) {
        const int n = it * 32 + wave * 2 + half;
        const f4v v = c4[(size_t)n * DVEC + sub];
        float p = v.x * wc.x + v.y * wc.y + v.z * wc.z + v.w * wc.w;
        #pragma unroll
        for (int m = 1; m < 32; m <<= 1) p += __shfl_xor(p, m, 64);  // in-half
        if (sub == 0) sm[n] = T_SCALE * p;
    }
    __syncthreads();

    // ---- Phase 2: softmax over sm[0..2047], entirely on-chip ----
    const float a0 = sm[tid];
    const float a1 = sm[tid + NTHR];
    float mx = fmaxf(a0, a1);
    #pragma unroll
    for (int m = 1; m < 64; m <<= 1) mx = fmaxf(mx, __shfl_xor(mx, m, 64));
    if (lane == 0) red[wave] = mx;
    __syncthreads();
    float gmax = red[0];
    #pragma unroll
    for (int i = 1; i < 16; ++i) gmax = fmaxf(gmax, red[i]);

    const float e0 = __expf(a0 - gmax);
    const float e1 = __expf(a1 - gmax);
    float s = e0 + e1;
    #pragma unroll
    for (int m = 1; m < 64; m <<= 1) s += __shfl_xor(s, m, 64);
    __syncthreads();                    // all done reading red (max)
    if (lane == 0) red[wave] = s;
    __syncthreads();
    float tot = red[0];
    #pragma unroll
    for (int i = 1; i < 16; ++i) tot += red[i];
    const float inv = 1.0f / tot;

    sm[tid]        = e0 * inv;
    sm[tid + NTHR] = e1 * inv;
    __syncthreads();

    // ---- Phase 3: out[n,:] = sm[n] * ctx[n,:] ----
    // Plain loads (cache-hot re-read) and PLAIN stores (absorb into L2 at
    // full rate; nt stores measured ~2 TB/s were the previous bottleneck).
    #pragma unroll 4
    for (int i = 0; i < (N_DIM * DVEC) / NTHR; ++i) {   // 64 iters
        const int f = i * NTHR + tid;
        const float w = sm[f >> 5];
        f4v v = c4[f];
        v *= w;
        o4[f] = v;
    }
}

extern "C" void kernel_launch(void* const* d_in, const int* in_sizes, int n_in,
                              void* d_out, int out_size, void* d_ws, size_t ws_size,
                              hipStream_t stream) {
    (void)in_sizes; (void)n_in; (void)out_size; (void)d_ws; (void)ws_size;
    // d_in[0] = targetsentence_emb (unused: cancels in softmax)
    // d_in[1] = context_emb, d_in[2] = W, d_in[3] = b (unused: cancels)
    const float* ctx = (const float*)d_in[1];
    const float* W   = (const float*)d_in[2];
    float* out       = (float*)d_out;

    hipLaunchKernelGGL(k_fused, dim3(B_DIM), dim3(NTHR), 0, stream,
                       ctx, W, out);
}

// Round 6
// 479.950 us; speedup vs baseline: 1.0856x; 1.0188x over previous
//
#include <hip/hip_runtime.h>

// HopAttentionLayer: B=256, T=64, N=2048, D=128, fp32.
// attention[b,n] = softmax_n( T * dot(context[b,n,:], W[D:2D]) )
//   (tgt_term[b] and T*b0 are constant over n -> cancel in softmax)
// out[b,n,d] = attention[b,n] * context[b,n,d]
//
// R8: TWO-DISPATCH SPLIT, each phase in its ideal grid shape.
//  - K_A (k_probs): per-batch scores + softmax (R7 phases 1+2), probs to
//    a 2 MiB workspace array (L2-resident hand-off). 256 x 1024.
//  - K_B (k_scale): pure scale stream in the copy-kernel shape that the
//    6.3-6.5 TB/s references use: 8192 retiring 256-thr blocks, 64 rows
//    each, no shuffles, no phase barrier, block refill -> no tail.
//    Reverse walk (LIFO: ctx just streamed through the 256 MiB L3 in K_A)
//    + nt stores so the output stream doesn't evict ctx lines.
//  - Diagnostic value: K_A's dur isolates the scores-read structure;
//    K_B's dur isolates the streaming-scale structure.

#define B_DIM 256
#define N_DIM 2048
#define D_DIM 128
#define DVEC  (D_DIM / 4)      // 32 float4 per row
#define T_SCALE 64.0f

typedef float f4v __attribute__((ext_vector_type(4)));

// ---- K_A: probs[b,n] = softmax_n( T * dot(ctx[b,n,:], Wc) ) ----
__global__ __launch_bounds__(1024)
void k_probs(const float* __restrict__ ctx, const float* __restrict__ W,
             float* __restrict__ probs) {
    const int tid  = threadIdx.x;
    const int wave = tid >> 6;          // 0..15
    const int lane = tid & 63;
    const int sub  = lane & 31;         // lane within half-wave
    const int half = lane >> 5;
    const int b    = blockIdx.x;

    __shared__ float sm[N_DIM];         // scores (8 KiB)
    __shared__ float red[16];

    const f4v* __restrict__ c4 = (const f4v*)ctx + (size_t)b * N_DIM * DVEC;
    const f4v wc = ((const f4v*)(W + D_DIM))[sub];

    // Phase 1: half-wave per row, one float4/lane, 5-step in-half reduce.
    #pragma unroll 4
    for (int it = 0; it < N_DIM / 32; ++it) {
        const int n = it * 32 + wave * 2 + half;
        const f4v v = c4[(size_t)n * DVEC + sub];
        float p = v.x * wc.x + v.y * wc.y + v.z * wc.z + v.w * wc.w;
        #pragma unroll
        for (int m = 1; m < 32; m <<= 1) p += __shfl_xor(p, m, 64);
        if (sub == 0) sm[n] = T_SCALE * p;
    }
    __syncthreads();

    // Phase 2: softmax over sm[0..2047], on-chip.
    const float a0 = sm[tid];
    const float a1 = sm[tid + 1024];
    float mx = fmaxf(a0, a1);
    #pragma unroll
    for (int m = 1; m < 64; m <<= 1) mx = fmaxf(mx, __shfl_xor(mx, m, 64));
    if (lane == 0) red[wave] = mx;
    __syncthreads();
    float gmax = red[0];
    #pragma unroll
    for (int i = 1; i < 16; ++i) gmax = fmaxf(gmax, red[i]);

    const float e0 = __expf(a0 - gmax);
    const float e1 = __expf(a1 - gmax);
    float s = e0 + e1;
    #pragma unroll
    for (int m = 1; m < 64; m <<= 1) s += __shfl_xor(s, m, 64);
    __syncthreads();
    if (lane == 0) red[wave] = s;
    __syncthreads();
    float tot = red[0];
    #pragma unroll
    for (int i = 1; i < 16; ++i) tot += red[i];
    const float inv = 1.0f / tot;

    float* pb = probs + (size_t)b * N_DIM;
    pb[tid]        = e0 * inv;          // coalesced 4 B/lane
    pb[tid + 1024] = e1 * inv;
}

// ---- K_B: out[r,:] = probs[r] * ctx[r,:], copy-shaped stream ----
__global__ __launch_bounds__(256)
void k_scale(const float* __restrict__ ctx, const float* __restrict__ probs,
             float* __restrict__ out) {
    const int tid = threadIdx.x;
    const int rb  = gridDim.x - 1 - blockIdx.x;     // reverse (LIFO vs K_A)
    const size_t base_row = (size_t)rb * 64;

    __shared__ float sp[64];
    if (tid < 64) sp[tid] = probs[base_row + tid];
    __syncthreads();

    const f4v* __restrict__ c4 = (const f4v*)ctx + base_row * DVEC;
    f4v*       __restrict__ o4 = (f4v*)out + base_row * DVEC;

    #pragma unroll
    for (int i = 0; i < 8; ++i) {                   // 64 rows = 2048 f4
        const int f = i * 256 + tid;
        const float w = sp[f >> 5];
        f4v v = c4[f];                              // plain: let L3 serve
        v *= w;
        __builtin_nontemporal_store(v, &o4[f]);     // don't evict ctx
    }
}

extern "C" void kernel_launch(void* const* d_in, const int* in_sizes, int n_in,
                              void* d_out, int out_size, void* d_ws, size_t ws_size,
                              hipStream_t stream) {
    (void)in_sizes; (void)n_in; (void)out_size; (void)ws_size;
    // d_in[0] = targetsentence_emb (unused: cancels in softmax)
    // d_in[1] = context_emb, d_in[2] = W, d_in[3] = b (unused: cancels)
    const float* ctx = (const float*)d_in[1];
    const float* W   = (const float*)d_in[2];
    float* out       = (float*)d_out;
    float* probs     = (float*)d_ws;    // B*N floats = 2 MiB

    hipLaunchKernelGGL(k_probs, dim3(B_DIM), dim3(1024), 0, stream,
                       ctx, W, probs);
    hipLaunchKernelGGL(k_scale, dim3(B_DIM * N_DIM / 64), dim3(256), 0, stream,
                       ctx, probs, out);
}

// Round 7
// 479.259 us; speedup vs baseline: 1.0871x; 1.0014x over previous
//
#include <hip/hip_runtime.h>

// HopAttentionLayer: B=256, T=64, N=2048, D=128, fp32.
// attention[b,n] = softmax_n( T * dot(context[b,n,:], W[D:2D]) )
//   (tgt_term[b] and T*b0 are constant over n -> cancel in softmax)
// out[b,n,d] = attention[b,n] * context[b,n,d]
//
// R9: R3 fused structure, phase 1 rebuilt SHUFFLE-FREE.
// Evidence: every scores pass (any grid shape) reads at ~2 TB/s while
// fillBuffer writes at 6.5. Shared trait: a convergent __shfl_xor chain
// glued to each load -> compiler won't keep loads in flight across it
// (R3 VGPR=20 ~ 1 load outstanding; R5's 16-load batch got re-serialized
// to VGPR=36). Fix: phase 1 = LDS-staged tiles.
//  - staging: copy-identical coalesced f4 loads, 2/thread/tile, issued
//    at loop top + sched_barrier(0) so they stay in flight across the
//    dot phase (T14 async-stage split; regs carried over the barrier)
//  - dot: per-thread 8-float slice from LDS (stride 132: 16B-aligned pad,
//    conflict-free at b128 minimum), zero cross-lane ops
//  - combine: 16 partials/row summed by 64 threads via small LDS array
// Phases 2 (LDS softmax) and 3 (nt re-read+scale+store) unchanged from
// R3, the best measured variant (177 us).

#define B_DIM 256
#define N_DIM 2048
#define D_DIM 128
#define DVEC  (D_DIM / 4)      // 32 float4 per row
#define NTHR  1024             // 16 waves
#define TILE  64               // rows per staging tile
#define NTILE (N_DIM / TILE)   // 32 tiles per batch
#define LSTR  132              // padded LDS row stride in floats (528 B, 16B-aligned)
#define T_SCALE 64.0f

typedef float f4v __attribute__((ext_vector_type(4)));

__global__ __launch_bounds__(NTHR)
void k_fused(const float* __restrict__ ctx, const float* __restrict__ W,
             float* __restrict__ out) {
    const int tid  = threadIdx.x;
    const int wave = tid >> 6;          // 0..15 = k-slice q
    const int lane = tid & 63;          // = row within tile (dot phase)
    const int b    = blockIdx.x;

    __shared__ float tb[TILE * LSTR];   // 33 KiB staging tile
    __shared__ float sm[N_DIM];         // 8 KiB scores -> probabilities
    __shared__ float ps[16 * TILE];     // 4 KiB partial dots
    __shared__ float red[16];

    const f4v* __restrict__ c4 = (const f4v*)ctx + (size_t)b * N_DIM * DVEC;
    f4v*       __restrict__ o4 = (f4v*)out + (size_t)b * N_DIM * DVEC;

    // This thread's 8-float Wc slice (k = wave*8 .. wave*8+7).
    const f4v wc0 = ((const f4v*)(W + D_DIM))[wave * 2];
    const f4v wc1 = ((const f4v*)(W + D_DIM))[wave * 2 + 1];

    // Staging coords: thread writes f4 #tid and #(1024+tid) of the tile.
    const int sr = tid >> 5;            // staging row 0..31 (i=0); +32 for i=1
    const int sc = (tid & 31) * 4;      // float col within row

    // ---- prologue: stage tile 0 ----
    {
        f4v r0 = c4[tid];
        f4v r1 = c4[1024 + tid];
        *(f4v*)&tb[sr * LSTR + sc]        = r0;
        *(f4v*)&tb[(32 + sr) * LSTR + sc] = r1;
    }
    __syncthreads();

    // ---- Phase 1: 32 tiles, loads for t+1 in flight across dot of t ----
    #pragma unroll 1
    for (int t = 0; t < NTILE; ++t) {
        f4v n0, n1;
        if (t < NTILE - 1) {
            const int gb = (t + 1) * (TILE * DVEC);      // 2048 f4 per tile
            n0 = c4[gb + tid];
            n1 = c4[gb + 1024 + tid];
        }
        __builtin_amdgcn_sched_barrier(0);  // pin loads above the dot

        // dot: row=lane, k-slice=wave; conflict-free (stride 132)
        const float* rb = &tb[lane * LSTR + wave * 8];
        const f4v a = *(const f4v*)rb;
        const f4v c = *(const f4v*)(rb + 4);
        const float p = a.x * wc0.x + a.y * wc0.y + a.z * wc0.z + a.w * wc0.w
                      + c.x * wc1.x + c.y * wc1.y + c.z * wc1.z + c.w * wc1.w;
        ps[wave * TILE + lane] = p;
        __syncthreads();

        if (tid < TILE) {                   // combine 16 partials per row
            float s = 0.f;
            #pragma unroll
            for (int q = 0; q < 16; ++q) s += ps[q * TILE + tid];
            sm[t * TILE + tid] = T_SCALE * s;
        }
        if (t < NTILE - 1) {                // ds_write next tile (regs held)
            *(f4v*)&tb[sr * LSTR + sc]        = n0;
            *(f4v*)&tb[(32 + sr) * LSTR + sc] = n1;
        }
        __syncthreads();
    }

    // ---- Phase 2: softmax over sm[0..2047], on-chip (R3 code) ----
    const float a0 = sm[tid];
    const float a1 = sm[tid + NTHR];
    float mx = fmaxf(a0, a1);
    #pragma unroll
    for (int m = 1; m < 64; m <<= 1) mx = fmaxf(mx, __shfl_xor(mx, m, 64));
    if (lane == 0) red[wave] = mx;
    __syncthreads();
    float gmax = red[0];
    #pragma unroll
    for (int i = 1; i < 16; ++i) gmax = fmaxf(gmax, red[i]);

    const float e0 = __expf(a0 - gmax);
    const float e1 = __expf(a1 - gmax);
    float s = e0 + e1;
    #pragma unroll
    for (int m = 1; m < 64; m <<= 1) s += __shfl_xor(s, m, 64);
    __syncthreads();                    // all done reading red (max)
    if (lane == 0) red[wave] = s;
    __syncthreads();
    float tot = red[0];
    #pragma unroll
    for (int i = 1; i < 16; ++i) tot += red[i];
    const float inv = 1.0f / tot;

    sm[tid]        = e0 * inv;
    sm[tid + NTHR] = e1 * inv;
    __syncthreads();

    // ---- Phase 3: out[n,:] = sm[n] * ctx[n,:] (R3 code: nt load/store) ----
    #pragma unroll 4
    for (int i = 0; i < (N_DIM * DVEC) / NTHR; ++i) {   // 64 iters
        const int f = i * NTHR + tid;
        const float w = sm[f >> 5];
        f4v v = __builtin_nontemporal_load(&c4[f]);
        v *= w;
        __builtin_nontemporal_store(v, &o4[f]);
    }
}

extern "C" void kernel_launch(void* const* d_in, const int* in_sizes, int n_in,
                              void* d_out, int out_size, void* d_ws, size_t ws_size,
                              hipStream_t stream) {
    (void)in_sizes; (void)n_in; (void)out_size; (void)d_ws; (void)ws_size;
    // d_in[0] = targetsentence_emb (unused: cancels in softmax)
    // d_in[1] = context_emb, d_in[2] = W, d_in[3] = b (unused: cancels)
    const float* ctx = (const float*)d_in[1];
    const float* W   = (const float*)d_in[2];
    float* out       = (float*)d_out;

    hipLaunchKernelGGL(k_fused, dim3(B_DIM), dim3(NTHR), 0, stream,
                       ctx, W, out);
}